// Round 2
// baseline (575.712 us; speedup 1.0000x reference)
//
#include <hip/hip_runtime.h>
#include <cstdint>

// B=32, T=2048, D=1024.  scores[b,t] = v · relu(W_h·hidden[b] + W_e·enc[b,t] + bias)
// out = softmax_T(scores).
// R5: GEMM ported to 256-row / 8-wave / 8-phase counted-vmcnt schedule (T2+T3+T4+T5):
// grid 256 blocks (1/CU), each block owns 256 A-rows, 4 serial 256-col N-passes,
// K-tiles of 64 split into two 32-k halves; per tile 4 phases x {ds_read frags,
// stage 1 half-tile (2 gload_lds/thread), [vmcnt(4) @ phases 1,3], barrier,
// lgkmcnt(0), setprio, 16 MFMA, setprio, barrier}. vmcnt never drains to 0 in the
// main loop. LDS 132KB: A/B 2buf x 2half x [256x32] bf16 with XOR swizzle
// (perm = q ^ ((cl>>1)&3); residual 2-way conflicts are free). Reg-resident score
// accumulation, per-pass relu·v folds, dedicated red[] LDS for the final reduce.

#define GLOBAL_AS __attribute__((address_space(1)))
#define LDS_AS    __attribute__((address_space(3)))

typedef __bf16 bf16x8 __attribute__((ext_vector_type(8)));
typedef float  f32x4  __attribute__((ext_vector_type(4)));

__device__ __forceinline__ unsigned int f2bf(float x) {
    unsigned int u = __builtin_bit_cast(unsigned int, x);
    u += 0x7fffu + ((u >> 16) & 1u);   // RNE
    return u >> 16;
}

// ---- enc fp32 -> bf16, 8 elems/thread, pure streaming ----
__global__ __launch_bounds__(256) void k_convert_enc(const float4* __restrict__ in,
                                                     uint4* __restrict__ out) {
    size_t idx = (size_t)blockIdx.x * 256 + threadIdx.x;
    float4 f0 = in[idx * 2];
    float4 f1 = in[idx * 2 + 1];
    uint4 o;
    o.x = f2bf(f0.x) | (f2bf(f0.y) << 16);
    o.y = f2bf(f0.z) | (f2bf(f0.w) << 16);
    o.z = f2bf(f1.x) | (f2bf(f1.y) << 16);
    o.w = f2bf(f1.z) | (f2bf(f1.w) << 16);
    out[idx] = o;
}

// ---- W_e = W[:,1024:2048] fp32 -> bf16 [1024 x 1024], k contiguous ----
__global__ __launch_bounds__(256) void k_convert_we(const float* __restrict__ W,
                                                    uint2* __restrict__ out) {
    int idx = blockIdx.x * 256 + threadIdx.x;
    int i = idx * 4;
    int n = i >> 10, k = i & 1023;
    const float4 f = *(const float4*)(W + (size_t)n * 2048 + 1024 + k);
    uint2 o;
    o.x = f2bf(f.x) | (f2bf(f.y) << 16);
    o.y = f2bf(f.z) | (f2bf(f.w) << 16);
    out[idx] = o;
}

// ---- u[b,d] = hidden[b,:]·W[d,0:1024] + bias[d] ; one block per d, split-K ----
__global__ __launch_bounds__(256) void k_hidden_proj(const float* __restrict__ hidden,
                                                     const float* __restrict__ W,
                                                     const float* __restrict__ bias,
                                                     float* __restrict__ u) {
    __shared__ float wrow[1024];
    __shared__ float red[256];
    const int tid = threadIdx.x, d = blockIdx.x;
    ((float4*)wrow)[tid] = ((const float4*)(W + (size_t)d * 2048))[tid];
    __syncthreads();
    const int b = tid & 31, kc = tid >> 5;
    const float* h = hidden + b * 1024 + kc * 128;
    const float* w = wrow + kc * 128;
    float acc = 0.f;
    #pragma unroll 8
    for (int i = 0; i < 128; i += 4) {
        float4 hv = *(const float4*)(h + i);
        acc += w[i] * hv.x + w[i + 1] * hv.y + w[i + 2] * hv.z + w[i + 3] * hv.w;
    }
    red[tid] = acc;
    __syncthreads();
    if (tid < 32) {
        float s = 0.f;
        #pragma unroll
        for (int j = 0; j < 8; j++) s += red[j * 32 + tid];
        u[tid * 1024 + d] = s + bias[d];
    }
}

// ================= 8-phase GEMM + fused relu·v score =================
// grid 256 blocks x 512 threads. Block: A rows mb*256..+255, passes p=0..3 over
// n = p*256..+255, K = 1024 as 16 tiles of 64 (2 k-halves of 32 each).

#define STAGE_A(S, h, kk) do {                                                          \
    __builtin_amdgcn_global_load_lds(                                                   \
        (GLOBAL_AS void*)(size_t)(Ab + arow0 + (kk) + (h) * 32),                        \
        (LDS_AS void*)(&As[S][h][c0 * 512]), 16, 0, 0);                                 \
    __builtin_amdgcn_global_load_lds(                                                   \
        (GLOBAL_AS void*)(size_t)(Ab + arow1 + (kk) + (h) * 32),                        \
        (LDS_AS void*)(&As[S][h][c0 * 512 + 512]), 16, 0, 0);                           \
} while (0)

#define STAGE_B(S, h, kk, nbn) do {                                                     \
    __builtin_amdgcn_global_load_lds(                                                   \
        (GLOBAL_AS void*)(size_t)(Bw + (size_t)(nbn) * 262144 + brow0 + (kk) + (h) * 32), \
        (LDS_AS void*)(&Bs[S][h][c0 * 512]), 16, 0, 0);                                 \
    __builtin_amdgcn_global_load_lds(                                                   \
        (GLOBAL_AS void*)(size_t)(Bw + (size_t)(nbn) * 262144 + brow1 + (kk) + (h) * 32), \
        (LDS_AS void*)(&Bs[S][h][c0 * 512 + 512]), 16, 0, 0);                           \
} while (0)

#define PHASE_MFMA(jp)                                                                  \
    __builtin_amdgcn_s_barrier();                                                       \
    asm volatile("s_waitcnt lgkmcnt(0)" ::: "memory");                                  \
    __builtin_amdgcn_sched_barrier(0);                                                  \
    __builtin_amdgcn_s_setprio(1);                                                      \
    _Pragma("unroll")                                                                   \
    for (int i = 0; i < 8; i++) {                                                       \
        acc[i][2 * (jp)]     = __builtin_amdgcn_mfma_f32_16x16x32_bf16(                 \
            afr[i], bfr[0], acc[i][2 * (jp)], 0, 0, 0);                                 \
        acc[i][2 * (jp) + 1] = __builtin_amdgcn_mfma_f32_16x16x32_bf16(                 \
            afr[i], bfr[1], acc[i][2 * (jp) + 1], 0, 0, 0);                             \
    }                                                                                   \
    __builtin_amdgcn_s_setprio(0);                                                      \
    __builtin_amdgcn_s_barrier();

// Tile t: compute from buf C, stage tile t+1's halves into buf S (order A0,B0,A1,B1).
// vmcnt(4) at ends of phases 1 and 3: "all but 4 newest loads retired" — the data
// read after the next barrier is always older than the 4 newest stage-loads.
#define TILE(C, S, kst, nbn) do {                                                       \
    { /* P0: h=0, j 0-1 */                                                              \
        const unsigned short* Ap = As[C][0];                                            \
        const unsigned short* Bp = Bs[C][0];                                            \
        _Pragma("unroll")                                                               \
        for (int i = 0; i < 8; i++) afr[i] = *(const bf16x8*)(Ap + aBase + i * 512);    \
        bfr[0] = *(const bf16x8*)(Bp + bBase);                                          \
        bfr[1] = *(const bf16x8*)(Bp + bBase + 512);                                    \
        STAGE_A(S, 0, kst);                                                             \
        PHASE_MFMA(0)                                                                   \
    }                                                                                   \
    { /* P1: h=0, j 2-3 */                                                              \
        const unsigned short* Bp = Bs[C][0];                                            \
        bfr[0] = *(const bf16x8*)(Bp + bBase + 1024);                                   \
        bfr[1] = *(const bf16x8*)(Bp + bBase + 1536);                                   \
        STAGE_B(S, 0, kst, nbn);                                                        \
        asm volatile("s_waitcnt vmcnt(4)" ::: "memory");                                \
        PHASE_MFMA(1)                                                                   \
    }                                                                                   \
    { /* P2: h=1, j 0-1 */                                                              \
        const unsigned short* Ap = As[C][1];                                            \
        const unsigned short* Bp = Bs[C][1];                                            \
        _Pragma("unroll")                                                               \
        for (int i = 0; i < 8; i++) afr[i] = *(const bf16x8*)(Ap + aBase + i * 512);    \
        bfr[0] = *(const bf16x8*)(Bp + bBase);                                          \
        bfr[1] = *(const bf16x8*)(Bp + bBase + 512);                                    \
        STAGE_A(S, 1, kst);                                                             \
        PHASE_MFMA(0)                                                                   \
    }                                                                                   \
    { /* P3: h=1, j 2-3 */                                                              \
        const unsigned short* Bp = Bs[C][1];                                            \
        bfr[0] = *(const bf16x8*)(Bp + bBase + 1024);                                   \
        bfr[1] = *(const bf16x8*)(Bp + bBase + 1536);                                   \
        STAGE_B(S, 1, kst, nbn);                                                        \
        asm volatile("s_waitcnt vmcnt(4)" ::: "memory");                                \
        PHASE_MFMA(1)                                                                   \
    }                                                                                   \
} while (0)

__global__ __launch_bounds__(512, 2) void k_gemm_score(
        const unsigned short* __restrict__ Ab,   // enc bf16 [65536,1024]
        const unsigned short* __restrict__ Bw,   // W_e bf16 [1024,1024]
        const float* __restrict__ u,             // [32,1024] (incl. bias)
        const float* __restrict__ v,             // [1024]
        float* __restrict__ scores) {            // [65536]
    __shared__ __align__(16) unsigned short As[2][2][8192];  // 64 KB
    __shared__ __align__(16) unsigned short Bs[2][2][8192];  // 64 KB
    __shared__ float red[4][256];                            // 4 KB (dedicated)

    const int tid  = threadIdx.x;
    const int wave = tid >> 6;
    const int lane = tid & 63;
    const int mb   = blockIdx.x;                 // 0..255
    const int wm = wave & 1, wn = wave >> 1;     // wn 0..3
    const int q = lane >> 4, cl = lane & 15;
    const int bidx = mb >> 3;                    // batch = (mb*256)/2048

    // fragment LDS bases (shorts) within a [256 x 32] half-buffer
    const int perm  = (q ^ ((cl >> 1) & 3)) << 3;
    const int aBase = (wm * 128 + cl) * 32 + perm;
    const int bBase = (wn * 64 + cl) * 32 + perm;

    // staging geometry: 16 chunks of 1KB per half-tile; wave does chunks c0, c0+1.
    // chunk c covers rows c*16 + (lane>>2); slot = lane&3; granule = slot ^ ((row>>1)&3)
    const int c0 = wave * 2;
    const int g8 = (((lane & 3) ^ ((lane >> 3) & 3)) << 3);
    const int rowA0 = c0 * 16 + (lane >> 2);
    const size_t arow0 = (size_t)(mb * 256 + rowA0) * 1024 + g8;
    const size_t arow1 = arow0 + 16 * 1024;
    const size_t brow0 = (size_t)rowA0 * 1024 + g8;
    const size_t brow1 = brow0 + 16 * 1024;

    f32x4 acc[8][4];
    float sacc[8][4];
    bf16x8 afr[8], bfr[2];
    #pragma unroll
    for (int i = 0; i < 8; i++)
        #pragma unroll
        for (int r = 0; r < 4; r++) sacc[i][r] = 0.f;

    // prologue: stage tile 0 (pass 0) halves; vmcnt(4) completes the h0 pair.
    STAGE_A(0, 0, 0);
    STAGE_B(0, 0, 0, 0);
    STAGE_A(0, 1, 0);
    STAGE_B(0, 1, 0, 0);
    asm volatile("s_waitcnt vmcnt(4)" ::: "memory");
    __builtin_amdgcn_s_barrier();

    for (int p = 0; p < 4; p++) {
        #pragma unroll
        for (int i = 0; i < 8; i++)
            #pragma unroll
            for (int j = 0; j < 4; j++) acc[i][j] = (f32x4){0.f, 0.f, 0.f, 0.f};

        for (int it = 0; it < 8; it++) {
            const int k1 = (2 * it + 1) * 64;          // stage k for tile 2it+1
            TILE(0, 1, k1, p);
            const int last = (it == 7);
            const int k2  = last ? 0 : (2 * it + 2) * 64;
            const int nb2 = last ? ((p < 3) ? p + 1 : 3) : p;
            TILE(1, 0, k2, nb2);
        }

        // fold this pass's 256 n's into sacc: += relu(E + u) · v
        float vv[4], uu[4];
        #pragma unroll
        for (int j = 0; j < 4; j++) {
            int n = p * 256 + wn * 64 + j * 16 + cl;
            vv[j] = v[n];
            uu[j] = u[bidx * 1024 + n];
        }
        #pragma unroll
        for (int i = 0; i < 8; i++)
            #pragma unroll
            for (int r = 0; r < 4; r++) {
                float s = sacc[i][r];
                #pragma unroll
                for (int j = 0; j < 4; j++)
                    s += fmaxf(acc[i][j][r] + uu[j], 0.f) * vv[j];
                sacc[i][r] = s;
            }
    }

    // reduce: 16 cl-lanes (shfl), then 4 wn-waves (LDS), store 256 scores
    #pragma unroll
    for (int i = 0; i < 8; i++)
        #pragma unroll
        for (int r = 0; r < 4; r++) {
            float s = sacc[i][r];
            s += __shfl_xor(s, 1);
            s += __shfl_xor(s, 2);
            s += __shfl_xor(s, 4);
            s += __shfl_xor(s, 8);
            if (cl == 0) red[wn][wm * 128 + i * 16 + q * 4 + r] = s;
        }
    __syncthreads();
    if (tid < 256) {
        scores[(size_t)mb * 256 + tid] =
            red[0][tid] + red[1][tid] + red[2][tid] + red[3][tid];
    }
}

// ---- softmax over T=2048 per batch ----
__global__ __launch_bounds__(256) void k_softmax(const float* __restrict__ scores,
                                                 float* __restrict__ out) {
    __shared__ float red[4];
    int b = blockIdx.x;
    int t0 = threadIdx.x;
    int wave = threadIdx.x >> 6, lane = threadIdx.x & 63;
    const float* s0 = scores + b * 2048;
    float vals[8];
    float lmax = -1e30f;
    #pragma unroll
    for (int i = 0; i < 8; i++) {
        int t = t0 + i * 256;
        vals[i] = s0[t];
        lmax = fmaxf(lmax, vals[i]);
    }
    for (int o = 32; o > 0; o >>= 1) lmax = fmaxf(lmax, __shfl_xor(lmax, o));
    if (lane == 0) red[wave] = lmax;
    __syncthreads();
    float gmax = fmaxf(fmaxf(red[0], red[1]), fmaxf(red[2], red[3]));
    float lsum = 0.f;
    #pragma unroll
    for (int i = 0; i < 8; i++) {
        vals[i] = expf(vals[i] - gmax);
        lsum += vals[i];
    }
    for (int o = 32; o > 0; o >>= 1) lsum += __shfl_xor(lsum, o);
    __syncthreads();
    if (lane == 0) red[wave] = lsum;
    __syncthreads();
    float inv = 1.0f / (red[0] + red[1] + red[2] + red[3]);
    #pragma unroll
    for (int i = 0; i < 8; i++) out[b * 2048 + t0 + i * 256] = vals[i] * inv;
}

extern "C" void kernel_launch(void* const* d_in, const int* in_sizes, int n_in,
                              void* d_out, int out_size, void* d_ws, size_t ws_size,
                              hipStream_t stream) {
    const float* hidden = (const float*)d_in[0];  // [32,1024]
    const float* enc    = (const float*)d_in[1];  // [32,2048,1024]
    const float* W      = (const float*)d_in[2];  // [1024,2048]
    const float* bias   = (const float*)d_in[3];  // [1024]
    const float* v      = (const float*)d_in[4];  // [1024]
    float* out = (float*)d_out;                   // [32,1,2048]

    char* ws = (char*)d_ws;
    unsigned short* encb = (unsigned short*)ws;                       // 128 MB bf16 A
    unsigned short* Web  = (unsigned short*)(ws + 134217728);         // 2 MB bf16 W_e
    float* u      = (float*)(ws + 134217728 + 2097152);               // 128 KB
    float* scores = (float*)(ws + 134217728 + 2097152 + 131072);      // 256 KB

    k_convert_enc<<<32768, 256, 0, stream>>>((const float4*)enc, (uint4*)encb);
    k_convert_we<<<1024, 256, 0, stream>>>(W, (uint2*)Web);
    k_hidden_proj<<<1024, 256, 0, stream>>>(hidden, W, bias, u);
    k_gemm_score<<<256, 512, 0, stream>>>(encb, Web, u, v, scores);
    k_softmax<<<32, 256, 0, stream>>>(scores, out);
}

// Round 4
// 570.305 us; speedup vs baseline: 1.0095x; 1.0095x over previous
//
#include <hip/hip_runtime.h>
#include <cstdint>

// B=32, T=2048, D=1024.  scores[b,t] = v · relu(W_h·hidden[b] + W_e·enc[b,t] + bias)
// out = softmax_T(scores).
// R6: fix R5's spill regression (WRITE_SIZE 4.6MB -> 58MB = scratch). Keep the
// verified 8-phase counted-vmcnt schedule but split N across BLOCKS not serial
// passes: grid 1024 = (256 mb x 4 nb), each block BM=256 x BN=256 x K=1024.
// The relu-v fold runs ONCE in the epilogue, fused into the shfl reduce (no sacc
// array live across the K-loop) -> K-loop register shape == m201 template, no
// spill under launch_bounds(512,2). Partials to scores4[4][65536] (deterministic,
// no atomics); softmax sums 4. Bijective XCD swizzle co-locates the 4 nb-blocks
// of an mb on one XCD (A-tile L2-shared; 8 tiles x 512KB = 4MB = L2/XCD).
// R7: byte-identical resubmit — R6 bench was an infra failure (container failed
// twice, same flake as R4/round-0 which hit the known-good baseline).

#define GLOBAL_AS __attribute__((address_space(1)))
#define LDS_AS    __attribute__((address_space(3)))

typedef __bf16 bf16x8 __attribute__((ext_vector_type(8)));
typedef float  f32x4  __attribute__((ext_vector_type(4)));

__device__ __forceinline__ unsigned int f2bf(float x) {
    unsigned int u = __builtin_bit_cast(unsigned int, x);
    u += 0x7fffu + ((u >> 16) & 1u);   // RNE
    return u >> 16;
}

// ---- enc fp32 -> bf16, 8 elems/thread, pure streaming ----
__global__ __launch_bounds__(256) void k_convert_enc(const float4* __restrict__ in,
                                                     uint4* __restrict__ out) {
    size_t idx = (size_t)blockIdx.x * 256 + threadIdx.x;
    float4 f0 = in[idx * 2];
    float4 f1 = in[idx * 2 + 1];
    uint4 o;
    o.x = f2bf(f0.x) | (f2bf(f0.y) << 16);
    o.y = f2bf(f0.z) | (f2bf(f0.w) << 16);
    o.z = f2bf(f1.x) | (f2bf(f1.y) << 16);
    o.w = f2bf(f1.z) | (f2bf(f1.w) << 16);
    out[idx] = o;
}

// ---- W_e = W[:,1024:2048] fp32 -> bf16 [1024 x 1024], k contiguous ----
__global__ __launch_bounds__(256) void k_convert_we(const float* __restrict__ W,
                                                    uint2* __restrict__ out) {
    int idx = blockIdx.x * 256 + threadIdx.x;
    int i = idx * 4;
    int n = i >> 10, k = i & 1023;
    const float4 f = *(const float4*)(W + (size_t)n * 2048 + 1024 + k);
    uint2 o;
    o.x = f2bf(f.x) | (f2bf(f.y) << 16);
    o.y = f2bf(f.z) | (f2bf(f.w) << 16);
    out[idx] = o;
}

// ---- u[b,d] = hidden[b,:]·W[d,0:1024] + bias[d] ; one block per d, split-K ----
__global__ __launch_bounds__(256) void k_hidden_proj(const float* __restrict__ hidden,
                                                     const float* __restrict__ W,
                                                     const float* __restrict__ bias,
                                                     float* __restrict__ u) {
    __shared__ float wrow[1024];
    __shared__ float red[256];
    const int tid = threadIdx.x, d = blockIdx.x;
    ((float4*)wrow)[tid] = ((const float4*)(W + (size_t)d * 2048))[tid];
    __syncthreads();
    const int b = tid & 31, kc = tid >> 5;
    const float* h = hidden + b * 1024 + kc * 128;
    const float* w = wrow + kc * 128;
    float acc = 0.f;
    #pragma unroll 8
    for (int i = 0; i < 128; i += 4) {
        float4 hv = *(const float4*)(h + i);
        acc += w[i] * hv.x + w[i + 1] * hv.y + w[i + 2] * hv.z + w[i + 3] * hv.w;
    }
    red[tid] = acc;
    __syncthreads();
    if (tid < 32) {
        float s = 0.f;
        #pragma unroll
        for (int j = 0; j < 8; j++) s += red[j * 32 + tid];
        u[tid * 1024 + d] = s + bias[d];
    }
}

// ================= 8-phase GEMM + fused relu·v score =================
// grid 1024 blocks x 512 threads. Block (mb,nb): A rows mb*256..+255,
// B cols nb*256..+255, K = 1024 as 16 tiles of 64 (2 k-halves of 32 each).

#define STAGE_A(S, h, kk) do {                                                          \
    __builtin_amdgcn_global_load_lds(                                                   \
        (GLOBAL_AS void*)(size_t)(Ab + arow0 + (kk) + (h) * 32),                        \
        (LDS_AS void*)(&As[S][h][c0 * 512]), 16, 0, 0);                                 \
    __builtin_amdgcn_global_load_lds(                                                   \
        (GLOBAL_AS void*)(size_t)(Ab + arow1 + (kk) + (h) * 32),                        \
        (LDS_AS void*)(&As[S][h][c0 * 512 + 512]), 16, 0, 0);                           \
} while (0)

#define STAGE_B(S, h, kk) do {                                                          \
    __builtin_amdgcn_global_load_lds(                                                   \
        (GLOBAL_AS void*)(size_t)(Bbase + brow0 + (kk) + (h) * 32),                     \
        (LDS_AS void*)(&Bs[S][h][c0 * 512]), 16, 0, 0);                                 \
    __builtin_amdgcn_global_load_lds(                                                   \
        (GLOBAL_AS void*)(size_t)(Bbase + brow1 + (kk) + (h) * 32),                     \
        (LDS_AS void*)(&Bs[S][h][c0 * 512 + 512]), 16, 0, 0);                           \
} while (0)

#define PHASE_MFMA(jp)                                                                  \
    __builtin_amdgcn_s_barrier();                                                       \
    asm volatile("s_waitcnt lgkmcnt(0)" ::: "memory");                                  \
    __builtin_amdgcn_sched_barrier(0);                                                  \
    __builtin_amdgcn_s_setprio(1);                                                      \
    _Pragma("unroll")                                                                   \
    for (int i = 0; i < 8; i++) {                                                       \
        acc[i][2 * (jp)]     = __builtin_amdgcn_mfma_f32_16x16x32_bf16(                 \
            afr[i], bfr[0], acc[i][2 * (jp)], 0, 0, 0);                                 \
        acc[i][2 * (jp) + 1] = __builtin_amdgcn_mfma_f32_16x16x32_bf16(                 \
            afr[i], bfr[1], acc[i][2 * (jp) + 1], 0, 0, 0);                             \
    }                                                                                   \
    __builtin_amdgcn_s_setprio(0);                                                      \
    __builtin_amdgcn_s_barrier();

// Tile t: compute from buf C, stage tile t+1's halves into buf S (order A0,B0,A1,B1).
// vmcnt(4) at ends of phases 1 and 3: "all but 4 newest loads retired" — the data
// read after the next barrier is always older than the 4 newest stage-loads.
#define TILE(C, S, kst) do {                                                            \
    { /* P0: h=0, j 0-1 */                                                              \
        const unsigned short* Ap = As[C][0];                                            \
        const unsigned short* Bp = Bs[C][0];                                            \
        _Pragma("unroll")                                                               \
        for (int i = 0; i < 8; i++) afr[i] = *(const bf16x8*)(Ap + aBase + i * 512);    \
        bfr[0] = *(const bf16x8*)(Bp + bBase);                                          \
        bfr[1] = *(const bf16x8*)(Bp + bBase + 512);                                    \
        STAGE_A(S, 0, kst);                                                             \
        PHASE_MFMA(0)                                                                   \
    }                                                                                   \
    { /* P1: h=0, j 2-3 */                                                              \
        const unsigned short* Bp = Bs[C][0];                                            \
        bfr[0] = *(const bf16x8*)(Bp + bBase + 1024);                                   \
        bfr[1] = *(const bf16x8*)(Bp + bBase + 1536);                                   \
        STAGE_B(S, 0, kst);                                                             \
        asm volatile("s_waitcnt vmcnt(4)" ::: "memory");                                \
        PHASE_MFMA(1)                                                                   \
    }                                                                                   \
    { /* P2: h=1, j 0-1 */                                                              \
        const unsigned short* Ap = As[C][1];                                            \
        const unsigned short* Bp = Bs[C][1];                                            \
        _Pragma("unroll")                                                               \
        for (int i = 0; i < 8; i++) afr[i] = *(const bf16x8*)(Ap + aBase + i * 512);    \
        bfr[0] = *(const bf16x8*)(Bp + bBase);                                          \
        bfr[1] = *(const bf16x8*)(Bp + bBase + 512);                                    \
        STAGE_A(S, 1, kst);                                                             \
        PHASE_MFMA(0)                                                                   \
    }                                                                                   \
    { /* P3: h=1, j 2-3 */                                                              \
        const unsigned short* Bp = Bs[C][1];                                            \
        bfr[0] = *(const bf16x8*)(Bp + bBase + 1024);                                   \
        bfr[1] = *(const bf16x8*)(Bp + bBase + 1536);                                   \
        STAGE_B(S, 1, kst);                                                             \
        asm volatile("s_waitcnt vmcnt(4)" ::: "memory");                                \
        PHASE_MFMA(1)                                                                   \
    }                                                                                   \
} while (0)

__global__ __launch_bounds__(512, 2) void k_gemm_score(
        const unsigned short* __restrict__ Ab,   // enc bf16 [65536,1024]
        const unsigned short* __restrict__ Bw,   // W_e bf16 [1024,1024]
        const float* __restrict__ u,             // [32,1024] (incl. bias)
        const float* __restrict__ v,             // [1024]
        float* __restrict__ scores4) {           // [4,65536]
    __shared__ __align__(16) unsigned short As[2][2][8192];  // 64 KB
    __shared__ __align__(16) unsigned short Bs[2][2][8192];  // 64 KB
    __shared__ float red[4][256];                            // 4 KB (dedicated)

    const int tid  = threadIdx.x;
    const int wave = tid >> 6;
    const int lane = tid & 63;
    // bijective XCD swizzle: nwg=1024 % 8 == 0. Blocks on one XCD get a
    // contiguous logical range -> the 4 nb-blocks of an mb share that XCD's L2.
    const int bid  = blockIdx.x;
    const int lg   = (bid & 7) * 128 + (bid >> 3);
    const int mb   = lg >> 2;                    // 0..255
    const int nb   = lg & 3;                     // 0..3
    const int wm = wave & 1, wn = wave >> 1;     // wn 0..3
    const int q = lane >> 4, cl = lane & 15;
    const int bidx = mb >> 3;                    // batch = (mb*256)/2048

    // fragment LDS bases (shorts) within a [256 x 32] half-buffer
    const int perm  = (q ^ ((cl >> 1) & 3)) << 3;
    const int aBase = (wm * 128 + cl) * 32 + perm;
    const int bBase = (wn * 64 + cl) * 32 + perm;

    // staging geometry: 16 chunks of 1KB per half-tile; wave does chunks c0, c0+1.
    // chunk c covers rows c*16 + (lane>>2); slot = lane&3; granule = slot ^ ((row>>1)&3)
    const int c0 = wave * 2;
    const int g8 = (((lane & 3) ^ ((lane >> 3) & 3)) << 3);
    const int rowA0 = c0 * 16 + (lane >> 2);
    const size_t arow0 = (size_t)(mb * 256 + rowA0) * 1024 + g8;
    const size_t arow1 = arow0 + 16 * 1024;
    const size_t brow0 = (size_t)rowA0 * 1024 + g8;
    const size_t brow1 = brow0 + 16 * 1024;
    const unsigned short* Bbase = Bw + (size_t)nb * 262144;

    f32x4 acc[8][4];
    bf16x8 afr[8], bfr[2];
    #pragma unroll
    for (int i = 0; i < 8; i++)
        #pragma unroll
        for (int j = 0; j < 4; j++) acc[i][j] = (f32x4){0.f, 0.f, 0.f, 0.f};

    // prologue: stage tile 0 halves; vmcnt(4) completes the h0 pair.
    STAGE_A(0, 0, 0);
    STAGE_B(0, 0, 0);
    STAGE_A(0, 1, 0);
    STAGE_B(0, 1, 0);
    asm volatile("s_waitcnt vmcnt(4)" ::: "memory");
    __builtin_amdgcn_s_barrier();

    for (int it = 0; it < 8; it++) {
        const int k1 = (2 * it + 1) * 64;              // stage k for tile 2it+1
        TILE(0, 1, k1);
        const int k2 = (it == 7) ? 0 : (2 * it + 2) * 64;  // dummy re-stage on last
        TILE(1, 0, k2);
    }

    // epilogue: fold relu(E+u)·v and reduce, no loop-carried sacc.
    float vv[4], uu[4];
    #pragma unroll
    for (int j = 0; j < 4; j++) {
        int n = nb * 256 + wn * 64 + j * 16 + cl;
        vv[j] = v[n];
        uu[j] = u[bidx * 1024 + n];
    }
    #pragma unroll
    for (int i = 0; i < 8; i++)
        #pragma unroll
        for (int r = 0; r < 4; r++) {
            float s = 0.f;
            #pragma unroll
            for (int j = 0; j < 4; j++)
                s += fmaxf(acc[i][j][r] + uu[j], 0.f) * vv[j];
            s += __shfl_xor(s, 1);
            s += __shfl_xor(s, 2);
            s += __shfl_xor(s, 4);
            s += __shfl_xor(s, 8);
            if (cl == 0) red[wn][wm * 128 + i * 16 + q * 4 + r] = s;
        }
    __syncthreads();
    if (tid < 256) {
        scores4[(size_t)nb * 65536 + mb * 256 + tid] =
            red[0][tid] + red[1][tid] + red[2][tid] + red[3][tid];
    }
}

// ---- softmax over T=2048 per batch; sums the four nb-quarters ----
__global__ __launch_bounds__(256) void k_softmax(const float* __restrict__ scores4,
                                                 float* __restrict__ out) {
    __shared__ float red[4];
    int b = blockIdx.x;
    int t0 = threadIdx.x;
    int wave = threadIdx.x >> 6, lane = threadIdx.x & 63;
    const float* s0 = scores4 + b * 2048;
    float vals[8];
    float lmax = -1e30f;
    #pragma unroll
    for (int i = 0; i < 8; i++) {
        int t = t0 + i * 256;
        vals[i] = s0[t] + s0[65536 + t] + s0[131072 + t] + s0[196608 + t];
        lmax = fmaxf(lmax, vals[i]);
    }
    for (int o = 32; o > 0; o >>= 1) lmax = fmaxf(lmax, __shfl_xor(lmax, o));
    if (lane == 0) red[wave] = lmax;
    __syncthreads();
    float gmax = fmaxf(fmaxf(red[0], red[1]), fmaxf(red[2], red[3]));
    float lsum = 0.f;
    #pragma unroll
    for (int i = 0; i < 8; i++) {
        vals[i] = expf(vals[i] - gmax);
        lsum += vals[i];
    }
    for (int o = 32; o > 0; o >>= 1) lsum += __shfl_xor(lsum, o);
    __syncthreads();
    if (lane == 0) red[wave] = lsum;
    __syncthreads();
    float inv = 1.0f / (red[0] + red[1] + red[2] + red[3]);
    #pragma unroll
    for (int i = 0; i < 8; i++) out[b * 2048 + t0 + i * 256] = vals[i] * inv;
}

extern "C" void kernel_launch(void* const* d_in, const int* in_sizes, int n_in,
                              void* d_out, int out_size, void* d_ws, size_t ws_size,
                              hipStream_t stream) {
    const float* hidden = (const float*)d_in[0];  // [32,1024]
    const float* enc    = (const float*)d_in[1];  // [32,2048,1024]
    const float* W      = (const float*)d_in[2];  // [1024,2048]
    const float* bias   = (const float*)d_in[3];  // [1024]
    const float* v      = (const float*)d_in[4];  // [1024]
    float* out = (float*)d_out;                   // [32,1,2048]

    char* ws = (char*)d_ws;
    unsigned short* encb = (unsigned short*)ws;                       // 128 MB bf16 A
    unsigned short* Web  = (unsigned short*)(ws + 134217728);         // 2 MB bf16 W_e
    float* u       = (float*)(ws + 134217728 + 2097152);              // 128 KB
    float* scores4 = (float*)(ws + 134217728 + 2097152 + 131072);     // 1 MB

    k_convert_enc<<<32768, 256, 0, stream>>>((const float4*)enc, (uint4*)encb);
    k_convert_we<<<1024, 256, 0, stream>>>(W, (uint2*)Web);
    k_hidden_proj<<<1024, 256, 0, stream>>>(hidden, W, bias, u);
    k_gemm_score<<<1024, 512, 0, stream>>>(encb, Web, u, v, scores4);
    k_softmax<<<32, 256, 0, stream>>>(scores4, out);
}